// Round 3
// baseline (509.419 us; speedup 1.0000x reference)
//
#include <hip/hip_runtime.h>

#define VDIM 207
#define LDIM 128
#define VP 224            // padded V (multiple of 16, covers K-steps 7*32)
#define VL (VDIM*LDIM)    // 26496
#define NC 1024           // B*C = 32*32
#define NPOINT (32*VL)    // B*V*L = 847872
#define APITCH 232        // LDS row pitch (u16): 464B = 116 dwords -> <=2-way bank conflict, 16B aligned

typedef unsigned short u16;
typedef unsigned int u32;
typedef __attribute__((ext_vector_type(4))) float f32x4;
typedef __attribute__((ext_vector_type(8))) short s16x8;

__device__ __forceinline__ u16 f2bf(float f) {
  u32 u = __float_as_uint(f);
  return (u16)((u + 0x7FFFu + ((u >> 16) & 1u)) >> 16);  // RNE
}
__device__ __forceinline__ float bf2f(u16 h) {
  return __uint_as_float(((u32)h) << 16);
}

// ---------------- prep: AT[i][w][v] = bf16(A_i[v][w]) zero-padded to 224x224;
//                  WT[k][o] = W[o][k]  (k = 0..223, o = 0..31) ----------------
__global__ void k_prep(const float* __restrict__ A0, const float* __restrict__ A1,
                       const float* __restrict__ A2, const float* __restrict__ W,
                       u16* __restrict__ AT, float* __restrict__ WT) {
  int idx = blockIdx.x * 256 + threadIdx.x;
  if (idx < 3 * VP * VP) {
    int i = idx / (VP * VP);
    int r = idx % (VP * VP);
    int w = r / VP, v = r % VP;
    const float* A = (i == 0) ? A0 : ((i == 1) ? A1 : A2);
    float f = (w < VDIM && v < VDIM) ? A[v * VDIM + w] : 0.f;
    AT[idx] = f2bf(f);
  } else {
    int j = idx - 3 * VP * VP;
    if (j < VP * 32) {
      int k = j >> 5, o = j & 31;
      WT[j] = W[o * 224 + k];
    }
  }
}

// ---------------- transpose x -> xT bf16 [nc][l=128][v=224] ----------------
__global__ __launch_bounds__(256) void k_xt(const float* __restrict__ x,
                                            u16* __restrict__ xT) {
  __shared__ float tile[64 * 130];  // [64 v][128 l] padded stride 130
  int nc = blockIdx.x;
  const float* xs = x + (size_t)nc * VL;
  u16* xd = xT + (size_t)nc * (128 * VP);
  int tid = threadIdx.x;
  for (int ch = 0; ch < 4; ++ch) {
    int v0 = ch * 64;
    __syncthreads();
#pragma unroll
    for (int j = 0; j < 8; ++j) {
      int idx = j * 256 + tid;        // over [64][32 float4]
      int vr = idx >> 5, c4 = idx & 31;
      int v = v0 + vr;
      float4 val = make_float4(0.f, 0.f, 0.f, 0.f);
      if (v < VDIM) val = *(const float4*)(xs + (size_t)v * LDIM + c4 * 4);
      float* trow = &tile[vr * 130 + c4 * 4];
      *(float2*)(trow) = make_float2(val.x, val.y);
      *(float2*)(trow + 2) = make_float2(val.z, val.w);
    }
    __syncthreads();
    int l = tid >> 1, h = tid & 1;
    int vbase = v0 + h * 32;
    if (vbase < VP) {
      u32 wd[16];
#pragma unroll
      for (int j = 0; j < 16; ++j) {
        int v = vbase + 2 * j;
        float f0 = (v < VDIM) ? tile[(h * 32 + 2 * j) * 130 + l] : 0.f;
        float f1 = (v + 1 < VDIM) ? tile[(h * 32 + 2 * j + 1) * 130 + l] : 0.f;
        wd[j] = (u32)f2bf(f0) | ((u32)f2bf(f1) << 16);
      }
      uint4* dst = (uint4*)(xd + (size_t)l * VP + vbase);
#pragma unroll
      for (int t = 0; t < 4; ++t)
        dst[t] = make_uint4(wd[4 * t], wd[4 * t + 1], wd[4 * t + 2], wd[4 * t + 3]);
    }
  }
}

// ---------------- fused double-hop: z1 = A^T x, z2 = A^T z1 (per (n,c)) -------
// LDS: A_s[208][232] bf16 (full A resident) | z1T[128][232] bf16.
// hop0 B-frags stream from global xT (L2-resident slab); K-loops barrier-free.
__global__ __launch_bounds__(512, 2) void k_hops(const u16* __restrict__ xT,
                                                 const u16* __restrict__ AT,
                                                 u16* __restrict__ zbuf,
                                                 int i0, int icount) {
  __shared__ __align__(16) u16 smem[208 * APITCH + 128 * APITCH];  // 155,904 B
  u16* A_s = smem;
  u16* z1T = smem + 208 * APITCH;

  int tid = threadIdx.x;
  int lane = tid & 63, wid = tid >> 6;
  int lane15 = lane & 15, lgrp = lane >> 4;
  int wm = wid >> 2, wn = wid & 3;  // wave grid: 2 (M) x 4 (N)
  int NMT = 7 - wm;                 // wm0: rows 0..111 (7 tiles), wm1: 112..207 (6)
  int nc = blockIdx.x;
  const u16* xg = xT + (size_t)nc * (128 * VP);

  // zero z1T pad columns 208..223 once (hop1's K covers w in [0,224))
  if (tid < 256) {
    int l = tid >> 1, h = tid & 1;
    *(uint4*)(z1T + l * APITCH + 208 + h * 8) = make_uint4(0, 0, 0, 0);
  }

  int col0 = wn * 32 + lane15;        // n-tile 0 col (l)
  int col1 = col0 + 16;               // n-tile 1 col

  for (int ii = 0; ii < icount; ++ii) {
    int i = i0 + ii;
    const u16* Ag = AT + i * (VP * VP);
    // stage full A: 208 rows x 224 u16 = 208 x 28 uint4 = 5824
    for (int j = tid; j < 5824; j += 512) {
      int r = j / 28, cq = j - r * 28;
      *(uint4*)(A_s + r * APITCH + cq * 8) =
          *(const uint4*)(Ag + r * VP + cq * 8);
    }
    __syncthreads();  // (B1) A ready; also covers z1T zero-fill / prior-i reuse

    for (int hop = 0; hop < 2; ++hop) {
      f32x4 acc[14];
#pragma unroll
      for (int m = 0; m < 14; ++m) acc[m] = (f32x4){0.f, 0.f, 0.f, 0.f};

      for (int ks = 0; ks < 7; ++ks) {
        s16x8 b0, b1;
        if (hop == 0) {
          b0 = *(const s16x8*)(xg + (size_t)col0 * VP + ks * 32 + lgrp * 8);
          b1 = *(const s16x8*)(xg + (size_t)col1 * VP + ks * 32 + lgrp * 8);
        } else {
          b0 = *(const s16x8*)(z1T + col0 * APITCH + ks * 32 + lgrp * 8);
          b1 = *(const s16x8*)(z1T + col1 * APITCH + ks * 32 + lgrp * 8);
        }
#pragma unroll
        for (int mt = 0; mt < 7; ++mt) {
          if (mt < NMT) {
            int row = wm * 112 + mt * 16 + lane15;
            s16x8 afrag = *(const s16x8*)(A_s + row * APITCH + ks * 32 + lgrp * 8);
            asm("v_mfma_f32_16x16x32_bf16 %0, %1, %2, %0"
                : "+v"(acc[mt * 2 + 0])
                : "v"(afrag), "v"(b0));
            asm("v_mfma_f32_16x16x32_bf16 %0, %1, %2, %0"
                : "+v"(acc[mt * 2 + 1])
                : "v"(afrag), "v"(b1));
          }
        }
      }

      if (hop == 1) __syncthreads();  // (B3) hop1 A_s/z1T reads done before next i

      // epilogue: global z store (+ transposed LDS copy for hop1's B operand)
      int slot = 2 * ii + hop;
      u16* zg = zbuf + (size_t)slot * ((size_t)NC * VL) + (size_t)nc * VL;
#pragma unroll
      for (int mt = 0; mt < 7; ++mt) {
        if (mt < NMT) {
#pragma unroll
          for (int nt = 0; nt < 2; ++nt) {
            f32x4 a = acc[mt * 2 + nt];
            int col = wn * 32 + nt * 16 + lane15;     // l
            int wb = wm * 112 + mt * 16 + lgrp * 4;   // w base (4 consecutive)
            u16 u0 = f2bf(a.x), u1 = f2bf(a.y), u2 = f2bf(a.z), u3 = f2bf(a.w);
            if (hop == 0) {
              uint2 pk = make_uint2((u32)u0 | ((u32)u1 << 16),
                                    (u32)u2 | ((u32)u3 << 16));
              *(uint2*)(z1T + col * APITCH + wb) = pk;
            }
            if (wb + 0 < VDIM) zg[(wb + 0) * LDIM + col] = u0;
            if (wb + 1 < VDIM) zg[(wb + 1) * LDIM + col] = u1;
            if (wb + 2 < VDIM) zg[(wb + 2) * LDIM + col] = u2;
            if (wb + 3 < VDIM) zg[(wb + 3) * LDIM + col] = u3;
          }
        }
      }
      if (hop == 0) __syncthreads();  // (B2) z1T fully written before hop1 reads
    }
  }
}

// ---------------- channel mix: out = b + W0*x + sum_g Wg*z_g ----------------
// 2 points per thread; f32x4 accumulators; W rows via wave-uniform s_loads.
template <int MODE, int NZ>
__global__ __launch_bounds__(256, 4) void k_mix(const float* __restrict__ x,
                                                const u16* __restrict__ zb,
                                                const float* __restrict__ WT,
                                                const float* __restrict__ bias,
                                                float* __restrict__ out, int wk0) {
  int t = blockIdx.x * 256 + threadIdx.x;  // point-pair index, < NPOINT/2
  int pp = t * 2;
  int n = pp / VL;
  int rem = pp - n * VL;  // even
  float* op = out + (size_t)n * 32 * VL + rem;
  f32x4 a0[8], a1[8];

  if (MODE == 0) {
#pragma unroll
    for (int j = 0; j < 8; ++j) {
      f32x4 bv = *(const f32x4*)(bias + 4 * j);
      a0[j] = bv;
      a1[j] = bv;
    }
    const float* xp = x + (size_t)n * 32 * VL + rem;
#pragma unroll
    for (int c0 = 0; c0 < 32; c0 += 4) {
      float2 v[4];
#pragma unroll
      for (int q = 0; q < 4; ++q)
        v[q] = *(const float2*)(xp + (size_t)(c0 + q) * VL);
#pragma unroll
      for (int q = 0; q < 4; ++q) {
        const float* wv = WT + (c0 + q) * 32;
#pragma unroll
        for (int j = 0; j < 8; ++j) {
          f32x4 w4 = *(const f32x4*)(wv + 4 * j);
          a0[j] += w4 * v[q].x;
          a1[j] += w4 * v[q].y;
        }
      }
    }
  } else {
#pragma unroll
    for (int j = 0; j < 8; ++j) {
#pragma unroll
      for (int q = 0; q < 4; ++q) {
        float2 r = *(const float2*)(op + (size_t)(4 * j + q) * VL);
        a0[j][q] = r.x;
        a1[j][q] = r.y;
      }
    }
  }

#pragma unroll 1
  for (int g = 0; g < NZ; ++g) {
    const u16* zp = zb + ((size_t)g * NC + (size_t)n * 32) * VL + rem;
    const float* wg = WT + (wk0 + g * 32) * 32;
#pragma unroll
    for (int c0 = 0; c0 < 32; c0 += 4) {
      u32 zv[4];
#pragma unroll
      for (int q = 0; q < 4; ++q)
        zv[q] = *(const u32*)(zp + (size_t)(c0 + q) * VL);
#pragma unroll
      for (int q = 0; q < 4; ++q) {
        float f0 = bf2f((u16)(zv[q] & 0xFFFFu));
        float f1 = bf2f((u16)(zv[q] >> 16));
        const float* wv = wg + (c0 + q) * 32;
#pragma unroll
        for (int j = 0; j < 8; ++j) {
          f32x4 w4 = *(const f32x4*)(wv + 4 * j);
          a0[j] += w4 * f0;
          a1[j] += w4 * f1;
        }
      }
    }
  }

#pragma unroll
  for (int j = 0; j < 8; ++j) {
#pragma unroll
    for (int q = 0; q < 4; ++q) {
      float2 r;
      r.x = a0[j][q];
      r.y = a1[j][q];
      *(float2*)(op + (size_t)(4 * j + q) * VL) = r;
    }
  }
}

extern "C" void kernel_launch(void* const* d_in, const int* in_sizes, int n_in,
                              void* d_out, int out_size, void* d_ws, size_t ws_size,
                              hipStream_t stream) {
  const float* x = (const float*)d_in[0];
  const float* A0 = (const float*)d_in[1];
  const float* A1 = (const float*)d_in[2];
  const float* A2 = (const float*)d_in[3];
  const float* W = (const float*)d_in[4];
  const float* b = (const float*)d_in[5];
  float* out = (float*)d_out;

  const size_t xT_sz = (size_t)NC * 128 * VP * 2;  // 58,720,256
  const size_t AT_sz = (size_t)3 * VP * VP * 2;    // 301,056
  const size_t WT_sz = (size_t)VP * 32 * 4;        // 28,672
  const size_t slot_sz = (size_t)NC * VL * 2;      // 54,263,808

  char* wp = (char*)d_ws;
  u16* xT = (u16*)wp; wp += (xT_sz + 255) & ~(size_t)255;
  u16* AT = (u16*)wp; wp += (AT_sz + 255) & ~(size_t)255;
  float* WT = (float*)wp; wp += (WT_sz + 255) & ~(size_t)255;
  u16* zbuf = (u16*)wp;
  size_t base = (size_t)(wp - (char*)d_ws);
  bool bigws = ws_size >= base + 6 * slot_sz;

  const int mixgrid = NPOINT / 512;  // 1656 blocks, 2 points/thread

  k_prep<<<616, 256, 0, stream>>>(A0, A1, A2, W, AT, WT);
  k_xt<<<NC, 256, 0, stream>>>(x, xT);
  if (bigws) {
    k_hops<<<NC, 512, 0, stream>>>(xT, AT, zbuf, 0, 3);
    k_mix<0, 6><<<mixgrid, 256, 0, stream>>>(x, zbuf, WT, b, out, 32);
  } else {
    // low-workspace path: 2 z slots, accumulate per A-matrix
    k_mix<0, 0><<<mixgrid, 256, 0, stream>>>(x, nullptr, WT, b, out, 32);
    for (int i = 0; i < 3; ++i) {
      k_hops<<<NC, 512, 0, stream>>>(xT, AT, zbuf, i, 1);
      k_mix<1, 2><<<mixgrid, 256, 0, stream>>>(nullptr, zbuf, WT, nullptr, out,
                                               (1 + 2 * i) * 32);
    }
  }
}

// Round 6
// 355.137 us; speedup vs baseline: 1.4344x; 1.4344x over previous
//
#include <hip/hip_runtime.h>

#define VDIM 207
#define LDIM 128
#define VP 224            // padded V (multiple of 16, covers K-steps 7*32)
#define VL (VDIM*LDIM)    // 26496
#define NC 1024           // B*C = 32*32
#define NPOINT (32*VL)    // B*V*L = 847872
#define APITCH 232        // LDS row pitch (u16): 464B = 116 dwords -> <=2-way bank conflict, 16B aligned

typedef unsigned short u16;
typedef unsigned int u32;
typedef __attribute__((ext_vector_type(4))) float f32x4;
typedef __attribute__((ext_vector_type(8))) short s16x8;

__device__ __forceinline__ u16 f2bf(float f) {
  u32 u = __float_as_uint(f);
  return (u16)((u + 0x7FFFu + ((u >> 16) & 1u)) >> 16);  // RNE
}
__device__ __forceinline__ float bf2f(u16 h) {
  return __uint_as_float(((u32)h) << 16);
}

// ---------------- prep: AT[i][w][v] = bf16(A_i[v][w]) zero-padded to 224x224;
//   WT[k][o] = W[o][k] (f32, fallback path);  Wb[o][k] = bf16(W[o][k]) --------
__global__ void k_prep(const float* __restrict__ A0, const float* __restrict__ A1,
                       const float* __restrict__ A2, const float* __restrict__ W,
                       u16* __restrict__ AT, float* __restrict__ WT,
                       u16* __restrict__ Wb) {
  int idx = blockIdx.x * 256 + threadIdx.x;
  if (idx < 3 * VP * VP) {
    int i = idx / (VP * VP);
    int r = idx % (VP * VP);
    int w = r / VP, v = r % VP;
    const float* A = (i == 0) ? A0 : ((i == 1) ? A1 : A2);
    float f = (w < VDIM && v < VDIM) ? A[v * VDIM + w] : 0.f;
    AT[idx] = f2bf(f);
  } else {
    int j = idx - 3 * VP * VP;
    if (j < VP * 32) {
      int k = j >> 5, o = j & 31;
      WT[j] = W[o * 224 + k];
    } else if (j < 2 * VP * 32) {
      int j2 = j - VP * 32;     // Wb[o][k], same layout as W
      Wb[j2] = f2bf(W[j2]);
    }
  }
}

// ---------------- transpose x -> xT bf16 [nc][l=128][v=224] ----------------
__global__ __launch_bounds__(256) void k_xt(const float* __restrict__ x,
                                            u16* __restrict__ xT) {
  __shared__ float tile[64 * 130];  // [64 v][128 l] padded stride 130
  int nc = blockIdx.x;
  const float* xs = x + (size_t)nc * VL;
  u16* xd = xT + (size_t)nc * (128 * VP);
  int tid = threadIdx.x;
  for (int ch = 0; ch < 4; ++ch) {
    int v0 = ch * 64;
    __syncthreads();
#pragma unroll
    for (int j = 0; j < 8; ++j) {
      int idx = j * 256 + tid;        // over [64][32 float4]
      int vr = idx >> 5, c4 = idx & 31;
      int v = v0 + vr;
      float4 val = make_float4(0.f, 0.f, 0.f, 0.f);
      if (v < VDIM) val = *(const float4*)(xs + (size_t)v * LDIM + c4 * 4);
      float* trow = &tile[vr * 130 + c4 * 4];
      *(float2*)(trow) = make_float2(val.x, val.y);
      *(float2*)(trow + 2) = make_float2(val.z, val.w);
    }
    __syncthreads();
    int l = tid >> 1, h = tid & 1;
    int vbase = v0 + h * 32;
    if (vbase < VP) {
      u32 wd[16];
#pragma unroll
      for (int j = 0; j < 16; ++j) {
        int v = vbase + 2 * j;
        float f0 = (v < VDIM) ? tile[(h * 32 + 2 * j) * 130 + l] : 0.f;
        float f1 = (v + 1 < VDIM) ? tile[(h * 32 + 2 * j + 1) * 130 + l] : 0.f;
        wd[j] = (u32)f2bf(f0) | ((u32)f2bf(f1) << 16);
      }
      uint4* dst = (uint4*)(xd + (size_t)l * VP + vbase);
#pragma unroll
      for (int t = 0; t < 4; ++t)
        dst[t] = make_uint4(wd[4 * t], wd[4 * t + 1], wd[4 * t + 2], wd[4 * t + 3]);
    }
  }
}

// ---------------- fused double-hop: z1 = A^T x, z2 = A^T z1 (per (n,c)) -------
// VERBATIM R3 body (verified passing twice). LDS: A_s[208][232] | z1T[128][232].
__global__ __launch_bounds__(512, 2) void k_hops(const u16* __restrict__ xT,
                                                 const u16* __restrict__ AT,
                                                 u16* __restrict__ zbuf,
                                                 int i0, int icount) {
  __shared__ __align__(16) u16 smem[208 * APITCH + 128 * APITCH];  // 155,904 B
  u16* A_s = smem;
  u16* z1T = smem + 208 * APITCH;

  int tid = threadIdx.x;
  int lane = tid & 63, wid = tid >> 6;
  int lane15 = lane & 15, lgrp = lane >> 4;
  int wm = wid >> 2, wn = wid & 3;  // wave grid: 2 (M) x 4 (N)
  int NMT = 7 - wm;                 // wm0: rows 0..111 (7 tiles), wm1: 112..207 (6)
  int nc = blockIdx.x;
  const u16* xg = xT + (size_t)nc * (128 * VP);

  // zero z1T pad columns 208..223 once (hop1's K covers w in [0,224))
  if (tid < 256) {
    int l = tid >> 1, h = tid & 1;
    *(uint4*)(z1T + l * APITCH + 208 + h * 8) = make_uint4(0, 0, 0, 0);
  }

  int col0 = wn * 32 + lane15;        // n-tile 0 col (l)
  int col1 = col0 + 16;               // n-tile 1 col

  for (int ii = 0; ii < icount; ++ii) {
    int i = i0 + ii;
    const u16* Ag = AT + i * (VP * VP);
    // stage full A: 208 rows x 224 u16 = 208 x 28 uint4 = 5824
    for (int j = tid; j < 5824; j += 512) {
      int r = j / 28, cq = j - r * 28;
      *(uint4*)(A_s + r * APITCH + cq * 8) =
          *(const uint4*)(Ag + r * VP + cq * 8);
    }
    __syncthreads();  // (B1) A ready; also covers z1T zero-fill / prior-i reuse

    for (int hop = 0; hop < 2; ++hop) {
      f32x4 acc[14];
#pragma unroll
      for (int m = 0; m < 14; ++m) acc[m] = (f32x4){0.f, 0.f, 0.f, 0.f};

      for (int ks = 0; ks < 7; ++ks) {
        s16x8 b0, b1;
        if (hop == 0) {
          b0 = *(const s16x8*)(xg + (size_t)col0 * VP + ks * 32 + lgrp * 8);
          b1 = *(const s16x8*)(xg + (size_t)col1 * VP + ks * 32 + lgrp * 8);
        } else {
          b0 = *(const s16x8*)(z1T + col0 * APITCH + ks * 32 + lgrp * 8);
          b1 = *(const s16x8*)(z1T + col1 * APITCH + ks * 32 + lgrp * 8);
        }
#pragma unroll
        for (int mt = 0; mt < 7; ++mt) {
          if (mt < NMT) {
            int row = wm * 112 + mt * 16 + lane15;
            s16x8 afrag = *(const s16x8*)(A_s + row * APITCH + ks * 32 + lgrp * 8);
            asm("v_mfma_f32_16x16x32_bf16 %0, %1, %2, %0"
                : "+v"(acc[mt * 2 + 0])
                : "v"(afrag), "v"(b0));
            asm("v_mfma_f32_16x16x32_bf16 %0, %1, %2, %0"
                : "+v"(acc[mt * 2 + 1])
                : "v"(afrag), "v"(b1));
          }
        }
      }

      if (hop == 1) __syncthreads();  // (B3) hop1 A_s/z1T reads done before next i

      // epilogue: global z store (+ transposed LDS copy for hop1's B operand)
      int slot = 2 * ii + hop;
      u16* zg = zbuf + (size_t)slot * ((size_t)NC * VL) + (size_t)nc * VL;
#pragma unroll
      for (int mt = 0; mt < 7; ++mt) {
        if (mt < NMT) {
#pragma unroll
          for (int nt = 0; nt < 2; ++nt) {
            f32x4 a = acc[mt * 2 + nt];
            int col = wn * 32 + nt * 16 + lane15;     // l
            int wb = wm * 112 + mt * 16 + lgrp * 4;   // w base (4 consecutive)
            u16 u0 = f2bf(a.x), u1 = f2bf(a.y), u2 = f2bf(a.z), u3 = f2bf(a.w);
            if (hop == 0) {
              uint2 pk = make_uint2((u32)u0 | ((u32)u1 << 16),
                                    (u32)u2 | ((u32)u3 << 16));
              *(uint2*)(z1T + col * APITCH + wb) = pk;
            }
            if (wb + 0 < VDIM) zg[(wb + 0) * LDIM + col] = u0;
            if (wb + 1 < VDIM) zg[(wb + 1) * LDIM + col] = u1;
            if (wb + 2 < VDIM) zg[(wb + 2) * LDIM + col] = u2;
            if (wb + 3 < VDIM) zg[(wb + 3) * LDIM + col] = u3;
          }
        }
      }
      if (hop == 0) __syncthreads();  // (B2) z1T fully written before hop1 reads
    }
  }
}

// ---------------- MFMA channel mix v2: out[n,o,p] = b[o] + sum_k Wb[o,k] h[k,p]
// h transposed in LDS to hT[p][k] (k-contiguous), so the B-frag is the exact
// verified k_hops z1T pattern. W-frags reg-hoisted from global. No unions.
__global__ __launch_bounds__(256, 2) void k_mixm(const float* __restrict__ x,
                                                 const u16* __restrict__ zb,
                                                 const u16* __restrict__ Wb,
                                                 const float* __restrict__ bias,
                                                 float* __restrict__ out) {
  __shared__ __align__(16) u16 hT_s[128 * APITCH];  // [p][k] pitch 232 -> 59,392 B
  __shared__ __align__(16) u16 tile[32 * 136];      // [c][p] pitch 136 -> 8,704 B
  int tid = threadIdx.x;
  int bid = blockIdx.x;
  int n = bid / 207, pt = bid - n * 207;   // 207 p-tiles of 128 (26496 exact)
  int p0 = pt * 128;
  int lane = tid & 63, wn = tid >> 6;      // 4 waves split N=128 into 32-col strips
  int lane15 = lane & 15, lgrp = lane >> 4;

  // W fragments from global (L2-resident, 16B-aligned vector loads)
  s16x8 wa0[7], wa1[7];
#pragma unroll
  for (int ks = 0; ks < 7; ++ks) {
    wa0[ks] = *(const s16x8*)(Wb + lane15 * 224 + ks * 32 + lgrp * 8);
    wa1[ks] = *(const s16x8*)(Wb + (16 + lane15) * 224 + ks * 32 + lgrp * 8);
  }

  for (int g7 = 0; g7 < 7; ++g7) {
    if (g7 == 0) {
      // x group (channels 0..31): f32 -> bf16 into tile[c][p]
#pragma unroll
      for (int j0 = 0; j0 < 4; ++j0) {
        int j = j0 * 256 + tid;          // [32 c][32 float4]
        int c = j >> 5, q = j & 31;
        float4 v = *(const float4*)(x + (size_t)(n * 32 + c) * VL + p0 + q * 4);
        u32 lo = (u32)f2bf(v.x) | ((u32)f2bf(v.y) << 16);
        u32 hi = (u32)f2bf(v.z) | ((u32)f2bf(v.w) << 16);
        *(uint2*)(tile + c * 136 + q * 4) = make_uint2(lo, hi);
      }
    } else {
      int g = g7 - 1;                    // z slot g: channels 32*g7 .. +31
#pragma unroll
      for (int j0 = 0; j0 < 2; ++j0) {
        int j = j0 * 256 + tid;          // [32 c][16 uint4]
        int c = j >> 4, cq = j & 15;
        *(uint4*)(tile + c * 136 + cq * 8) =
            *(const uint4*)(zb + ((size_t)(g << 10) + n * 32 + c) * VL + p0 + cq * 8);
      }
    }
    __syncthreads();
    // transpose: hT[p][g7*32 + 2cp .. +1] = tile[2cp..+1][p]
#pragma unroll
    for (int j0 = 0; j0 < 8; ++j0) {
      int j = j0 * 256 + tid;            // [128 p][16 c-pairs]
      int cp = j & 15, p = j >> 4;
      u32 w = (u32)tile[(2 * cp) * 136 + p] |
              ((u32)tile[(2 * cp + 1) * 136 + p] << 16);
      *(u32*)(hT_s + p * APITCH + g7 * 32 + 2 * cp) = w;
    }
    __syncthreads();
  }

  f32x4 acc[2][2];
#pragma unroll
  for (int mt = 0; mt < 2; ++mt)
#pragma unroll
    for (int nt = 0; nt < 2; ++nt) acc[mt][nt] = (f32x4){0.f, 0.f, 0.f, 0.f};

#pragma unroll
  for (int ks = 0; ks < 7; ++ks) {
#pragma unroll
    for (int nt = 0; nt < 2; ++nt) {
      int colp = wn * 32 + nt * 16 + lane15;
      s16x8 bfrag = *(const s16x8*)(hT_s + colp * APITCH + ks * 32 + lgrp * 8);
      asm("v_mfma_f32_16x16x32_bf16 %0, %1, %2, %0"
          : "+v"(acc[0][nt]) : "v"(wa0[ks]), "v"(bfrag));
      asm("v_mfma_f32_16x16x32_bf16 %0, %1, %2, %0"
          : "+v"(acc[1][nt]) : "v"(wa1[ks]), "v"(bfrag));
    }
  }

  // epilogue: += bias, f32 store (C/D: col = lane&15, row = lgrp*4 + j)
#pragma unroll
  for (int mt = 0; mt < 2; ++mt) {
#pragma unroll
    for (int j = 0; j < 4; ++j) {
      int o = mt * 16 + lgrp * 4 + j;
      float bv = bias[o];
#pragma unroll
      for (int nt = 0; nt < 2; ++nt) {
        int p = p0 + wn * 32 + nt * 16 + lane15;
        out[(size_t)(n * 32 + o) * VL + p] = acc[mt][nt][j] + bv;
      }
    }
  }
}

// ---------------- VALU channel mix (low-workspace fallback only) ----------------
template <int MODE, int NZ>
__global__ __launch_bounds__(256, 4) void k_mix(const float* __restrict__ x,
                                                const u16* __restrict__ zb,
                                                const float* __restrict__ WT,
                                                const float* __restrict__ bias,
                                                float* __restrict__ out, int wk0) {
  int t = blockIdx.x * 256 + threadIdx.x;
  int pp = t * 2;
  int n = pp / VL;
  int rem = pp - n * VL;
  float* op = out + (size_t)n * 32 * VL + rem;
  f32x4 a0[8], a1[8];

  if (MODE == 0) {
#pragma unroll
    for (int j = 0; j < 8; ++j) {
      f32x4 bv = *(const f32x4*)(bias + 4 * j);
      a0[j] = bv;
      a1[j] = bv;
    }
    const float* xp = x + (size_t)n * 32 * VL + rem;
#pragma unroll
    for (int c0 = 0; c0 < 32; c0 += 4) {
      float2 v[4];
#pragma unroll
      for (int q = 0; q < 4; ++q)
        v[q] = *(const float2*)(xp + (size_t)(c0 + q) * VL);
#pragma unroll
      for (int q = 0; q < 4; ++q) {
        const float* wv = WT + (c0 + q) * 32;
#pragma unroll
        for (int j = 0; j < 8; ++j) {
          f32x4 w4 = *(const f32x4*)(wv + 4 * j);
          a0[j] += w4 * v[q].x;
          a1[j] += w4 * v[q].y;
        }
      }
    }
  } else {
#pragma unroll
    for (int j = 0; j < 8; ++j) {
#pragma unroll
      for (int q = 0; q < 4; ++q) {
        float2 r = *(const float2*)(op + (size_t)(4 * j + q) * VL);
        a0[j][q] = r.x;
        a1[j][q] = r.y;
      }
    }
  }

#pragma unroll 1
  for (int g = 0; g < NZ; ++g) {
    const u16* zp = zb + ((size_t)g * NC + (size_t)n * 32) * VL + rem;
    const float* wg = WT + (wk0 + g * 32) * 32;
#pragma unroll
    for (int c0 = 0; c0 < 32; c0 += 4) {
      u32 zv[4];
#pragma unroll
      for (int q = 0; q < 4; ++q)
        zv[q] = *(const u32*)(zp + (size_t)(c0 + q) * VL);
#pragma unroll
      for (int q = 0; q < 4; ++q) {
        float f0 = bf2f((u16)(zv[q] & 0xFFFFu));
        float f1 = bf2f((u16)(zv[q] >> 16));
        const float* wv = wg + (c0 + q) * 32;
#pragma unroll
        for (int j = 0; j < 8; ++j) {
          f32x4 w4 = *(const f32x4*)(wv + 4 * j);
          a0[j] += w4 * f0;
          a1[j] += w4 * f1;
        }
      }
    }
  }

#pragma unroll
  for (int j = 0; j < 8; ++j) {
#pragma unroll
    for (int q = 0; q < 4; ++q) {
      float2 r;
      r.x = a0[j][q];
      r.y = a1[j][q];
      *(float2*)(op + (size_t)(4 * j + q) * VL) = r;
    }
  }
}

extern "C" void kernel_launch(void* const* d_in, const int* in_sizes, int n_in,
                              void* d_out, int out_size, void* d_ws, size_t ws_size,
                              hipStream_t stream) {
  const float* x = (const float*)d_in[0];
  const float* A0 = (const float*)d_in[1];
  const float* A1 = (const float*)d_in[2];
  const float* A2 = (const float*)d_in[3];
  const float* W = (const float*)d_in[4];
  const float* b = (const float*)d_in[5];
  float* out = (float*)d_out;

  const size_t xT_sz = (size_t)NC * 128 * VP * 2;  // 58,720,256
  const size_t AT_sz = (size_t)3 * VP * VP * 2;    // 301,056
  const size_t WT_sz = (size_t)VP * 32 * 4;        // 28,672
  const size_t Wb_sz = (size_t)VP * 32 * 2;        // 14,336
  const size_t slot_sz = (size_t)NC * VL * 2;      // 54,263,808

  char* wp = (char*)d_ws;
  u16* xT = (u16*)wp; wp += (xT_sz + 255) & ~(size_t)255;
  u16* AT = (u16*)wp; wp += (AT_sz + 255) & ~(size_t)255;
  float* WT = (float*)wp; wp += (WT_sz + 255) & ~(size_t)255;
  u16* Wb = (u16*)wp; wp += (Wb_sz + 255) & ~(size_t)255;
  u16* zbuf = (u16*)wp;
  size_t base = (size_t)(wp - (char*)d_ws);
  bool bigws = ws_size >= base + 6 * slot_sz;

  k_prep<<<644, 256, 0, stream>>>(A0, A1, A2, W, AT, WT, Wb);
  k_xt<<<NC, 256, 0, stream>>>(x, xT);
  if (bigws) {
    k_hops<<<NC, 512, 0, stream>>>(xT, AT, zbuf, 0, 3);
    k_mixm<<<32 * 207, 256, 0, stream>>>(x, zbuf, Wb, b, out);
  } else {
    // low-workspace path: 2 z slots, accumulate per A-matrix (VALU k_mix)
    const int mixgrid = NPOINT / 512;
    k_mix<0, 0><<<mixgrid, 256, 0, stream>>>(x, nullptr, WT, b, out, 32);
    for (int i = 0; i < 3; ++i) {
      k_hops<<<NC, 512, 0, stream>>>(xT, AT, zbuf, i, 1);
      k_mix<1, 2><<<mixgrid, 256, 0, stream>>>(nullptr, zbuf, WT, nullptr, out,
                                               (1 + 2 * i) * 32);
    }
  }
}

// Round 7
// 333.207 us; speedup vs baseline: 1.5288x; 1.0658x over previous
//
#include <hip/hip_runtime.h>

#define VDIM 207
#define LDIM 128
#define VP 224            // padded V (multiple of 16, covers K-steps 7*32)
#define VL (VDIM*LDIM)    // 26496
#define NC 1024           // B*C = 32*32
#define NPOINT (32*VL)    // B*V*L = 847872
#define APITCH 232        // LDS row pitch (u16): 464 B/row
// byte-offset swizzle within a 464B row: flips bit 5 on odd rows.
// col_byte < 448 always -> result stays < 464 (in-row, bijective).
#define SWZ(row, colb) ((row) * 464 + ((colb) ^ (((row) & 1) << 5)))

typedef unsigned short u16;
typedef unsigned int u32;
typedef __attribute__((ext_vector_type(4))) float f32x4;
typedef __attribute__((ext_vector_type(8))) short s16x8;

__device__ __forceinline__ u16 f2bf(float f) {
  u32 u = __float_as_uint(f);
  return (u16)((u + 0x7FFFu + ((u >> 16) & 1u)) >> 16);  // RNE
}
__device__ __forceinline__ float bf2f(u16 h) {
  return __uint_as_float(((u32)h) << 16);
}

// ---------------- prep: AT[i][w][v] = bf16(A_i[v][w]) zero-padded to 224x224;
//   WT[k][o] = W[o][k] (f32, fallback path);  Wb[o][k] = bf16(W[o][k]) --------
__global__ void k_prep(const float* __restrict__ A0, const float* __restrict__ A1,
                       const float* __restrict__ A2, const float* __restrict__ W,
                       u16* __restrict__ AT, float* __restrict__ WT,
                       u16* __restrict__ Wb) {
  int idx = blockIdx.x * 256 + threadIdx.x;
  if (idx < 3 * VP * VP) {
    int i = idx / (VP * VP);
    int r = idx % (VP * VP);
    int w = r / VP, v = r % VP;
    const float* A = (i == 0) ? A0 : ((i == 1) ? A1 : A2);
    float f = (w < VDIM && v < VDIM) ? A[v * VDIM + w] : 0.f;
    AT[idx] = f2bf(f);
  } else {
    int j = idx - 3 * VP * VP;
    if (j < VP * 32) {
      int k = j >> 5, o = j & 31;
      WT[j] = W[o * 224 + k];
    } else if (j < 2 * VP * 32) {
      int j2 = j - VP * 32;     // Wb[o][k], same layout as W
      Wb[j2] = f2bf(W[j2]);
    }
  }
}

// ---------------- transpose x -> xT bf16 [nc][l=128][v=224] ----------------
__global__ __launch_bounds__(256) void k_xt(const float* __restrict__ x,
                                            u16* __restrict__ xT) {
  __shared__ float tile[64 * 130];  // [64 v][128 l] padded stride 130
  int nc = blockIdx.x;
  const float* xs = x + (size_t)nc * VL;
  u16* xd = xT + (size_t)nc * (128 * VP);
  int tid = threadIdx.x;
  for (int ch = 0; ch < 4; ++ch) {
    int v0 = ch * 64;
    __syncthreads();
#pragma unroll
    for (int j = 0; j < 8; ++j) {
      int idx = j * 256 + tid;        // over [64][32 float4]
      int vr = idx >> 5, c4 = idx & 31;
      int v = v0 + vr;
      float4 val = make_float4(0.f, 0.f, 0.f, 0.f);
      if (v < VDIM) val = *(const float4*)(xs + (size_t)v * LDIM + c4 * 4);
      float* trow = &tile[vr * 130 + c4 * 4];
      *(float2*)(trow) = make_float2(val.x, val.y);
      *(float2*)(trow + 2) = make_float2(val.z, val.w);
    }
    __syncthreads();
    int l = tid >> 1, h = tid & 1;
    int vbase = v0 + h * 32;
    if (vbase < VP) {
      u32 wd[16];
#pragma unroll
      for (int j = 0; j < 16; ++j) {
        int v = vbase + 2 * j;
        float f0 = (v < VDIM) ? tile[(h * 32 + 2 * j) * 130 + l] : 0.f;
        float f1 = (v + 1 < VDIM) ? tile[(h * 32 + 2 * j + 1) * 130 + l] : 0.f;
        wd[j] = (u32)f2bf(f0) | ((u32)f2bf(f1) << 16);
      }
      uint4* dst = (uint4*)(xd + (size_t)l * VP + vbase);
#pragma unroll
      for (int t = 0; t < 4; ++t)
        dst[t] = make_uint4(wd[4 * t], wd[4 * t + 1], wd[4 * t + 2], wd[4 * t + 3]);
    }
  }
}

// ---------------- fused double-hop v3: z1 = A^T x, z2 = A^T z1 (per (n,c)) ----
// 16 waves (4M x 4N), XOR bank swizzle on A_s / z1T, same math & barriers.
__global__ __launch_bounds__(1024, 4) void k_hops(const u16* __restrict__ xT,
                                                  const u16* __restrict__ AT,
                                                  u16* __restrict__ zbuf,
                                                  int i0, int icount) {
  __shared__ __align__(16) u16 smem[208 * APITCH + 128 * APITCH];  // 155,904 B
  char* A_b = (char*)smem;
  char* z_b = (char*)(smem + 208 * APITCH);

  int tid = threadIdx.x;
  int lane = tid & 63, wid = tid >> 6;       // wid 0..15
  int lane15 = lane & 15, lgrp = lane >> 4;
  int wm = wid >> 2, wn = wid & 3;           // wave grid: 4 (M) x 4 (N)
  int NMT = (wm == 0) ? 4 : 3;               // m-tiles per wave-row (4+3+3+3=13)
  int mbase = (wm == 0) ? 0 : (16 + wm * 48);  // rows: 0 / 64 / 112 / 160
  int nc = blockIdx.x;
  const u16* xg = xT + (size_t)nc * (128 * VP);

  // zero z1T pad columns 208..223 once (hop1's K covers w in [0,224))
  if (tid < 256) {
    int l = tid >> 1, h = tid & 1;
    *(uint4*)(z_b + SWZ(l, 416 + 16 * h)) = make_uint4(0, 0, 0, 0);
  }

  int col0 = wn * 32 + lane15;        // n-tile 0 col (l)
  int col1 = col0 + 16;               // n-tile 1 col

  for (int ii = 0; ii < icount; ++ii) {
    int i = i0 + ii;
    const u16* Ag = AT + i * (VP * VP);
    // stage full A: 208 rows x 28 uint4 = 5824
    for (int j = tid; j < 5824; j += 1024) {
      int r = j / 28, cq = j - r * 28;
      *(uint4*)(A_b + SWZ(r, cq * 16)) = *(const uint4*)(Ag + r * VP + cq * 8);
    }
    __syncthreads();  // (B1) A ready; also covers z1T zero-fill / prior-i reuse

    for (int hop = 0; hop < 2; ++hop) {
      f32x4 acc[4][2];
#pragma unroll
      for (int m = 0; m < 4; ++m)
#pragma unroll
        for (int nt = 0; nt < 2; ++nt) acc[m][nt] = (f32x4){0.f, 0.f, 0.f, 0.f};

      for (int ks = 0; ks < 7; ++ks) {
        int colb = ks * 64 + lgrp * 16;   // byte offset of this K-slice
        s16x8 b0, b1;
        if (hop == 0) {
          b0 = *(const s16x8*)(xg + (size_t)col0 * VP + ks * 32 + lgrp * 8);
          b1 = *(const s16x8*)(xg + (size_t)col1 * VP + ks * 32 + lgrp * 8);
        } else {
          b0 = *(const s16x8*)(z_b + SWZ(col0, colb));
          b1 = *(const s16x8*)(z_b + SWZ(col1, colb));
        }
#pragma unroll
        for (int mt = 0; mt < 4; ++mt) {
          if (mt < NMT) {
            int row = mbase + mt * 16 + lane15;
            s16x8 afrag = *(const s16x8*)(A_b + SWZ(row, colb));
            asm("v_mfma_f32_16x16x32_bf16 %0, %1, %2, %0"
                : "+v"(acc[mt][0])
                : "v"(afrag), "v"(b0));
            asm("v_mfma_f32_16x16x32_bf16 %0, %1, %2, %0"
                : "+v"(acc[mt][1])
                : "v"(afrag), "v"(b1));
          }
        }
      }

      if (hop == 1) __syncthreads();  // (B3) hop1 A_s/z1T reads done before next i

      // epilogue: global z store (+ transposed LDS copy for hop1's B operand)
      int slot = 2 * ii + hop;
      u16* zg = zbuf + (size_t)slot * ((size_t)NC * VL) + (size_t)nc * VL;
#pragma unroll
      for (int mt = 0; mt < 4; ++mt) {
        if (mt < NMT) {
#pragma unroll
          for (int nt = 0; nt < 2; ++nt) {
            f32x4 a = acc[mt][nt];
            int col = wn * 32 + nt * 16 + lane15;     // l
            int wb = mbase + mt * 16 + lgrp * 4;      // w base (4 consecutive)
            u16 u0 = f2bf(a.x), u1 = f2bf(a.y), u2 = f2bf(a.z), u3 = f2bf(a.w);
            if (hop == 0) {
              uint2 pk = make_uint2((u32)u0 | ((u32)u1 << 16),
                                    (u32)u2 | ((u32)u3 << 16));
              *(uint2*)(z_b + SWZ(col, wb * 2)) = pk;
            }
            if (wb + 0 < VDIM) zg[(wb + 0) * LDIM + col] = u0;
            if (wb + 1 < VDIM) zg[(wb + 1) * LDIM + col] = u1;
            if (wb + 2 < VDIM) zg[(wb + 2) * LDIM + col] = u2;
            if (wb + 3 < VDIM) zg[(wb + 3) * LDIM + col] = u3;
          }
        }
      }
      if (hop == 0) __syncthreads();  // (B2) z1T fully written before hop1 reads
    }
  }
}

// ---------------- MFMA channel mix v2: out[n,o,p] = b[o] + sum_k Wb[o,k] h[k,p]
// h transposed in LDS to hT[p][k] (k-contiguous). W-frags reg-hoisted. VERBATIM R6.
__global__ __launch_bounds__(256, 2) void k_mixm(const float* __restrict__ x,
                                                 const u16* __restrict__ zb,
                                                 const u16* __restrict__ Wb,
                                                 const float* __restrict__ bias,
                                                 float* __restrict__ out) {
  __shared__ __align__(16) u16 hT_s[128 * APITCH];  // [p][k] pitch 232 -> 59,392 B
  __shared__ __align__(16) u16 tile[32 * 136];      // [c][p] pitch 136 -> 8,704 B
  int tid = threadIdx.x;
  int bid = blockIdx.x;
  int n = bid / 207, pt = bid - n * 207;   // 207 p-tiles of 128 (26496 exact)
  int p0 = pt * 128;
  int lane = tid & 63, wn = tid >> 6;      // 4 waves split N=128 into 32-col strips
  int lane15 = lane & 15, lgrp = lane >> 4;

  // W fragments from global (L2-resident, 16B-aligned vector loads)
  s16x8 wa0[7], wa1[7];
#pragma unroll
  for (int ks = 0; ks < 7; ++ks) {
    wa0[ks] = *(const s16x8*)(Wb + lane15 * 224 + ks * 32 + lgrp * 8);
    wa1[ks] = *(const s16x8*)(Wb + (16 + lane15) * 224 + ks * 32 + lgrp * 8);
  }

  for (int g7 = 0; g7 < 7; ++g7) {
    if (g7 == 0) {
      // x group (channels 0..31): f32 -> bf16 into tile[c][p]
#pragma unroll
      for (int j0 = 0; j0 < 4; ++j0) {
        int j = j0 * 256 + tid;          // [32 c][32 float4]
        int c = j >> 5, q = j & 31;
        float4 v = *(const float4*)(x + (size_t)(n * 32 + c) * VL + p0 + q * 4);
        u32 lo = (u32)f2bf(v.x) | ((u32)f2bf(v.y) << 16);
        u32 hi = (u32)f2bf(v.z) | ((u32)f2bf(v.w) << 16);
        *(uint2*)(tile + c * 136 + q * 4) = make_uint2(lo, hi);
      }
    } else {
      int g = g7 - 1;                    // z slot g: channels 32*g7 .. +31
#pragma unroll
      for (int j0 = 0; j0 < 2; ++j0) {
        int j = j0 * 256 + tid;          // [32 c][16 uint4]
        int c = j >> 4, cq = j & 15;
        *(uint4*)(tile + c * 136 + cq * 8) =
            *(const uint4*)(zb + ((size_t)(g << 10) + n * 32 + c) * VL + p0 + cq * 8);
      }
    }
    __syncthreads();
    // transpose: hT[p][g7*32 + 2cp .. +1] = tile[2cp..+1][p]
#pragma unroll
    for (int j0 = 0; j0 < 8; ++j0) {
      int j = j0 * 256 + tid;            // [128 p][16 c-pairs]
      int cp = j & 15, p = j >> 4;
      u32 w = (u32)tile[(2 * cp) * 136 + p] |
              ((u32)tile[(2 * cp + 1) * 136 + p] << 16);
      *(u32*)(hT_s + p * APITCH + g7 * 32 + 2 * cp) = w;
    }
    __syncthreads();
  }

  f32x4 acc[2][2];
#pragma unroll
  for (int mt = 0; mt < 2; ++mt)
#pragma unroll
    for (int nt = 0; nt < 2; ++nt) acc[mt][nt] = (f32x4){0.f, 0.f, 0.f, 0.f};

#pragma unroll
  for (int ks = 0; ks < 7; ++ks) {
#pragma unroll
    for (int nt = 0; nt < 2; ++nt) {
      int colp = wn * 32 + nt * 16 + lane15;
      s16x8 bfrag = *(const s16x8*)(hT_s + colp * APITCH + ks * 32 + lgrp * 8);
      asm("v_mfma_f32_16x16x32_bf16 %0, %1, %2, %0"
          : "+v"(acc[0][nt]) : "v"(wa0[ks]), "v"(bfrag));
      asm("v_mfma_f32_16x16x32_bf16 %0, %1, %2, %0"
          : "+v"(acc[1][nt]) : "v"(wa1[ks]), "v"(bfrag));
    }
  }

  // epilogue: += bias, f32 store (C/D: col = lane&15, row = lgrp*4 + j)
#pragma unroll
  for (int mt = 0; mt < 2; ++mt) {
#pragma unroll
    for (int j = 0; j < 4; ++j) {
      int o = mt * 16 + lgrp * 4 + j;
      float bv = bias[o];
#pragma unroll
      for (int nt = 0; nt < 2; ++nt) {
        int p = p0 + wn * 32 + nt * 16 + lane15;
        out[(size_t)(n * 32 + o) * VL + p] = acc[mt][nt][j] + bv;
      }
    }
  }
}

// ---------------- VALU channel mix (low-workspace fallback only) ----------------
template <int MODE, int NZ>
__global__ __launch_bounds__(256, 4) void k_mix(const float* __restrict__ x,
                                                const u16* __restrict__ zb,
                                                const float* __restrict__ WT,
                                                const float* __restrict__ bias,
                                                float* __restrict__ out, int wk0) {
  int t = blockIdx.x * 256 + threadIdx.x;
  int pp = t * 2;
  int n = pp / VL;
  int rem = pp - n * VL;
  float* op = out + (size_t)n * 32 * VL + rem;
  f32x4 a0[8], a1[8];

  if (MODE == 0) {
#pragma unroll
    for (int j = 0; j < 8; ++j) {
      f32x4 bv = *(const f32x4*)(bias + 4 * j);
      a0[j] = bv;
      a1[j] = bv;
    }
    const float* xp = x + (size_t)n * 32 * VL + rem;
#pragma unroll
    for (int c0 = 0; c0 < 32; c0 += 4) {
      float2 v[4];
#pragma unroll
      for (int q = 0; q < 4; ++q)
        v[q] = *(const float2*)(xp + (size_t)(c0 + q) * VL);
#pragma unroll
      for (int q = 0; q < 4; ++q) {
        const float* wv = WT + (c0 + q) * 32;
#pragma unroll
        for (int j = 0; j < 8; ++j) {
          f32x4 w4 = *(const f32x4*)(wv + 4 * j);
          a0[j] += w4 * v[q].x;
          a1[j] += w4 * v[q].y;
        }
      }
    }
  } else {
#pragma unroll
    for (int j = 0; j < 8; ++j) {
#pragma unroll
      for (int q = 0; q < 4; ++q) {
        float2 r = *(const float2*)(op + (size_t)(4 * j + q) * VL);
        a0[j][q] = r.x;
        a1[j][q] = r.y;
      }
    }
  }

#pragma unroll 1
  for (int g = 0; g < NZ; ++g) {
    const u16* zp = zb + ((size_t)g * NC + (size_t)n * 32) * VL + rem;
    const float* wg = WT + (wk0 + g * 32) * 32;
#pragma unroll
    for (int c0 = 0; c0 < 32; c0 += 4) {
      u32 zv[4];
#pragma unroll
      for (int q = 0; q < 4; ++q)
        zv[q] = *(const u32*)(zp + (size_t)(c0 + q) * VL);
#pragma unroll
      for (int q = 0; q < 4; ++q) {
        float f0 = bf2f((u16)(zv[q] & 0xFFFFu));
        float f1 = bf2f((u16)(zv[q] >> 16));
        const float* wv = wg + (c0 + q) * 32;
#pragma unroll
        for (int j = 0; j < 8; ++j) {
          f32x4 w4 = *(const f32x4*)(wv + 4 * j);
          a0[j] += w4 * f0;
          a1[j] += w4 * f1;
        }
      }
    }
  }

#pragma unroll
  for (int j = 0; j < 8; ++j) {
#pragma unroll
    for (int q = 0; q < 4; ++q) {
      float2 r;
      r.x = a0[j][q];
      r.y = a1[j][q];
      *(float2*)(op + (size_t)(4 * j + q) * VL) = r;
    }
  }
}

extern "C" void kernel_launch(void* const* d_in, const int* in_sizes, int n_in,
                              void* d_out, int out_size, void* d_ws, size_t ws_size,
                              hipStream_t stream) {
  const float* x = (const float*)d_in[0];
  const float* A0 = (const float*)d_in[1];
  const float* A1 = (const float*)d_in[2];
  const float* A2 = (const float*)d_in[3];
  const float* W = (const float*)d_in[4];
  const float* b = (const float*)d_in[5];
  float* out = (float*)d_out;

  const size_t xT_sz = (size_t)NC * 128 * VP * 2;  // 58,720,256
  const size_t AT_sz = (size_t)3 * VP * VP * 2;    // 301,056
  const size_t WT_sz = (size_t)VP * 32 * 4;        // 28,672
  const size_t Wb_sz = (size_t)VP * 32 * 2;        // 14,336
  const size_t slot_sz = (size_t)NC * VL * 2;      // 54,263,808

  char* wp = (char*)d_ws;
  u16* xT = (u16*)wp; wp += (xT_sz + 255) & ~(size_t)255;
  u16* AT = (u16*)wp; wp += (AT_sz + 255) & ~(size_t)255;
  float* WT = (float*)wp; wp += (WT_sz + 255) & ~(size_t)255;
  u16* Wb = (u16*)wp; wp += (Wb_sz + 255) & ~(size_t)255;
  u16* zbuf = (u16*)wp;
  size_t base = (size_t)(wp - (char*)d_ws);
  bool bigws = ws_size >= base + 6 * slot_sz;

  k_prep<<<644, 256, 0, stream>>>(A0, A1, A2, W, AT, WT, Wb);
  k_xt<<<NC, 256, 0, stream>>>(x, xT);
  if (bigws) {
    k_hops<<<NC, 1024, 0, stream>>>(xT, AT, zbuf, 0, 3);
    k_mixm<<<32 * 207, 256, 0, stream>>>(x, zbuf, Wb, b, out);
  } else {
    // low-workspace path: 2 z slots, accumulate per A-matrix (VALU k_mix)
    const int mixgrid = NPOINT / 512;
    k_mix<0, 0><<<mixgrid, 256, 0, stream>>>(x, nullptr, WT, b, out, 32);
    for (int i = 0; i < 3; ++i) {
      k_hops<<<NC, 1024, 0, stream>>>(xT, AT, zbuf, i, 1);
      k_mix<1, 2><<<mixgrid, 256, 0, stream>>>(nullptr, zbuf, WT, nullptr, out,
                                               (1 + 2 * i) * 32);
    }
  }
}